// Round 13
// baseline (124.296 us; speedup 1.0000x reference)
//
#include <hip/hip_runtime.h>
#include <hip/hip_bf16.h>

// Fused 34->128->128->1 MLP, bf16 MFMA, transposed GEMMs.
// R23 = R21 (proven, 57.2us) + A0 double-buffer + gather/stage hoist.
// R22 post-mortem: L1-halving restructure NaN'd (3rd source-correct NaN on
// restructures; proven lineage 5/5 pass) -> optimize INSIDE R21's dataflow.
// Corrected ledger (57.2us = 6745 cyc/tile): LDS ~41%, MFMA ~45%/SIMD,
// VALU ~28% -> gap-bound. Largest identifiable serial gap: R21's stage
// window (bar2->bar1) holds gather-issue + immediate consume = ~400-600cyc
// exposed em_table latency + pack VALU with nothing else in the window.
// R23: A0 becomes [2][64][72] (LDS 35840B; 3 blocks = 107.5KB). Per tile:
//   bar1 | out(t-1) | ISSUE gathers(t+1, uses feA) + fe/x loads(t+2)
//        | L0(t) MFMAs (gathers drain underneath) | stage-finish(t+1):
//          lerp->pack->ds_write A0[buf^1] | epi0(t) | bar2 | L1,L2,PART |
// Barriers still 2/tile; stage latency+VALU now inside the busy window.
// Hazard audit: stage(t+1)->buf^1 vs L0(t) reads buf: disjoint buffers.
//   stage bytes 0..67 (cols 0..33) vs out-read bytes 128..135: disjoint.
//   L0(t) reads buf vs stage(t+2) writes buf: bar2(t)+bar1(t+1) between.
//   epi0(t) H0-writes vs L1(t) reads: bar2(t). L1(t) reads vs epi0(t+1)
//   writes: bar1(t+1). PART(t) (post-bar2) vs out-read(t) (post-bar1(t+1)):
//   ordered; out-read(t) drains at wave0's bar2(t+1) entry before PART(t+1).
// Kept verbatim: lgkm-only bar_lds (vmcnt in flight across barriers),
// deferred out-phase (R21), pk2c clamp-fused cvt, L2-as-MFMA (W2 in A row
// 0), biases ride first MFMA C, PART aliased at A0 buf0 bytes row*144+128,
// no own[] / no reg-frag-across-barrier (NaN cells), (256,3) rung.
// Spill tell: WRITE_SIZE == 3906.25KB <=> clean (peak liveness ~140 < 168).

using bf16x8 = __attribute__((ext_vector_type(8))) short;   // 8 bf16 = 4 VGPRs
using f32x4  = __attribute__((ext_vector_type(4))) float;   // MFMA C/D

#define NPTS    1000000
#define NUMEMB  6572
#define HID     128
#define M_IT    64          // points per block-iteration
#define A0S     72          // A0 row stride in bf16 (144B, 16B-aligned rows)
#define H0S     136         // H0 row stride in bf16 (272B, 16B-aligned rows)
#define TILES   (NPTS / M_IT)   // 15625 exactly
#define NBLOCKS 768         // 3 blocks/CU on 256 CUs (proven non-spill rung)

__device__ __forceinline__ unsigned short bf16r(float f) {
    unsigned u;
    __builtin_memcpy(&u, &f, 4);
    u = (u + 0x7fffu + ((u >> 16) & 1u)) >> 16;
    return (unsigned short)u;
}
__device__ __forceinline__ unsigned pk2(float a, float b) {
    // packed RNE f32x2 -> bf16x2 (v_cvt_pk_bf16_f32 on gfx950)
    float2 f2; f2.x = a; f2.y = b;
    __hip_bfloat162 h = __float22bfloat162_rn(f2);
    unsigned u;
    __builtin_memcpy(&u, &h, 4);
    return u;
}
__device__ __forceinline__ unsigned pk2c(float a, float b) {
    // packed cvt with VOP3 clamp: result clamped to [0,1] — fuses clamp01
    unsigned r;
    asm("v_cvt_pk_bf16_f32 %0, %1, %2 clamp" : "=v"(r) : "v"(a), "v"(b));
    return r;
}
// LDS-only barrier (R18-verified): waits DS queue, leaves vmem in flight.
__device__ __forceinline__ void bar_lds() {
    asm volatile("s_waitcnt lgkmcnt(0)\n\ts_barrier" ::: "memory");
}

__global__ __launch_bounds__(256, 3)
void mlp_fused(const float* __restrict__ x,
               const float* __restrict__ emb,
               const float* __restrict__ em_table,
               const float* __restrict__ W0, const float* __restrict__ b0,
               const float* __restrict__ W1, const float* __restrict__ b1,
               const float* __restrict__ W2, const float* __restrict__ b2,
               float* __restrict__ out)
{
    __shared__ __align__(16) unsigned short A0[2 * M_IT * A0S]; // dbuf 18432B
    __shared__ __align__(16) unsigned short H0[M_IT * H0S];     // 17408B
    // PART[p][w] aliased into A0 buffer0 bytes p*144 + 128 + w*4 (cols
    // 64..71 of rows 0..63): stage writes cols 0..33 only; L0 reads <=63.

    const int tid  = threadIdx.x;
    const int lane = tid & 63;
    const int nq   = tid >> 6;   // wave's physical hidden block [nq*32,+32)
    const int q    = lane >> 4;  // quad within wave
    const int cl   = lane & 15;
    const int p    = tid >> 2;   // staging: point within tile
    const int s    = tid & 3;    // staging: 8-dim segment of embedding

    // zero both A0 buffers once (cols 34..63 stay zero; build writes 0..33)
    for (int i = tid; i < 2 * M_IT * A0S; i += 256) A0[i] = 0;

    // ---- one-time: weight A-fragments (permuted cols) into registers ----
    const int hcol = nq * 32 + (cl >> 2) * 8 + (cl & 3);  // + hb*4
    // W0 logical row k: k<32 -> em row 2+k ; k==32 -> x row 0 ; k==33 -> 1.
    bf16x8 w0t[2][2];   // [hb][kt]
    for (int hb = 0; hb < 2; ++hb)
        for (int kt = 0; kt < 2; ++kt) {
            const int col = hcol + hb * 4;
            bf16x8 v;
            #pragma unroll
            for (int e = 0; e < 8; ++e) {
                const int k = kt * 32 + q * 8 + e;
                float val = 0.f;
                if (k < 32)       val = W0[(2 + k) * HID + col];
                else if (k == 32) val = W0[0 * HID + col];
                else if (k == 33) val = W0[1 * HID + col];
                v[e] = (short)bf16r(val);
            }
            w0t[hb][kt] = v;
        }

    // W1 ROTATED: w1r[hb][kk] holds rows kphys = ((nq+kk)&3)*32 + q*8 + e
    bf16x8 w1r[2][4];   // [hb][kk]
    for (int hb = 0; hb < 2; ++hb)
        for (int kk = 0; kk < 4; ++kk) {
            const int kt  = (nq + kk) & 3;
            const int col = hcol + hb * 4;
            bf16x8 v;
            #pragma unroll
            for (int e = 0; e < 8; ++e) {
                const int k = kt * 32 + q * 8 + e;
                v[e] = (short)bf16r(W1[k * HID + col]);
            }
            w1r[hb][kk] = v;
        }

    // biases indexed by this lane's physical h = nq*32 + q*8 + hb*4 + r
    f32x4 b0q[2], b1q[2];
    for (int hb = 0; hb < 2; ++hb)
        for (int r = 0; r < 4; ++r) {
            const int h = nq * 32 + q * 8 + hb * 4 + r;
            b0q[hb][r] = b0[h];
            b1q[hb][r] = b1[h];
        }
    // L2 A-frag: A[m][k] = (m==0) ? W2[nq*32 + q*8 + k_e] : 0.
    bf16x8 w2f;
    #pragma unroll
    for (int e = 0; e < 8; ++e)
        w2f[e] = (cl == 0) ? (short)bf16r(W2[nq * 32 + q * 8 + e]) : (short)0;
    const float bias2 = b2[0];

    // ---- prologue: fe/x for tile t, then cold stage into buffer 0 ----
    int t = blockIdx.x;
    float  feA;
    float2 xvA = {0.f, 0.f};
    {
        const int gp = t * M_IT + p;
        feA = emb[gp];
        if (s == 0) xvA = *(const float2*)(x + 2 * gp);
    }
    __syncthreads();   // A0 zeroing visible before first build (cold path)
    {
        const int e1 = (int)feA;
        const int e2 = (e1 + 1 < NUMEMB) ? e1 + 1 : NUMEMB - 1;
        const float r = feA - (float)e1;
        const float4* p1 = (const float4*)(em_table + e1 * 32 + s * 8);
        const float4* p2 = (const float4*)(em_table + e2 * 32 + s * 8);
        const float4 a0v = p1[0], a1v = p1[1];
        const float4 c0v = p2[0], c1v = p2[1];
        uint4 d;
        d.x = pk2(a0v.x + (c0v.x - a0v.x) * r, a0v.y + (c0v.y - a0v.y) * r);
        d.y = pk2(a0v.z + (c0v.z - a0v.z) * r, a0v.w + (c0v.w - a0v.w) * r);
        d.z = pk2(a1v.x + (c1v.x - a1v.x) * r, a1v.y + (c1v.y - a1v.y) * r);
        d.w = pk2(a1v.z + (c1v.z - a1v.z) * r, a1v.w + (c1v.w - a1v.w) * r);
        *(uint4*)&A0[p * A0S + s * 8] = d;
        if (s == 0) *(unsigned*)&A0[p * A0S + 32] = pk2(xvA.x, xvA.y);
    }
    // prefetch fe/x for tile t+NBLOCKS (consumed by in-loop gather issue)
    {
        int t1 = t + NBLOCKS; if (t1 >= TILES) t1 = t;
        const int gp = t1 * M_IT + p;
        feA = emb[gp];
        if (s == 0) xvA = *(const float2*)(x + 2 * gp);
    }

    int prev_base = -1;
    int buf = 0;
    for (; t < TILES; t += NBLOCKS) {
        const int base = t * M_IT;
        bar_lds();   // bar1: A0[buf] staged + PART(t-1) visible (LDS-only)

        // ---- deferred out-phase for tile t-1 (PART in buffer 0) ----
        if (prev_base >= 0 && tid < 64) {
            const float4 pv = *(const float4*)((const char*)A0 + tid * 144 + 128);
            const float zz = bias2 + pv.x + pv.y + pv.z + pv.w;
            out[prev_base + tid] = __builtin_amdgcn_rcpf(1.f + __expf(-zz));
        }

        // ---- issue gathers for tile t+1 (feA ready) + fe/x for t+2 ----
        const int ge1 = (int)feA;
        const int ge2 = (ge1 + 1 < NUMEMB) ? ge1 + 1 : NUMEMB - 1;
        const float frA = feA - (float)ge1;
        const float4* pg1 = (const float4*)(em_table + ge1 * 32 + s * 8);
        const float4* pg2 = (const float4*)(em_table + ge2 * 32 + s * 8);
        const float4 g1a = pg1[0], g1b = pg1[1];
        const float4 g2a = pg2[0], g2b = pg2[1];
        float feN;
        float2 xvN = {0.f, 0.f};
        {
            int t2 = t + 2 * NBLOCKS; if (t2 >= TILES) t2 = t;
            const int gp = t2 * M_IT + p;
            feN = emb[gp];
            if (s == 0) xvN = *(const float2*)(x + 2 * gp);
        }

        // ---- layer 0 (reads A0[buf]); gather latency drains underneath ----
        const int aB = buf * (M_IT * A0S);
        f32x4 acc[4][2];   // [pb][hb]
        #pragma unroll
        for (int pb = 0; pb < 4; ++pb) {
            const bf16x8 bf0 = *(const bf16x8*)
                &A0[aB + (pb * 16 + cl) * A0S + q * 8];
            const bf16x8 bf1 = *(const bf16x8*)
                &A0[aB + (pb * 16 + cl) * A0S + 32 + q * 8];
            #pragma unroll
            for (int hb = 0; hb < 2; ++hb) {
                f32x4 a = __builtin_amdgcn_mfma_f32_16x16x32_bf16(
                    w0t[hb][0], bf0, b0q[hb], 0, 0, 0);
                acc[pb][hb] = __builtin_amdgcn_mfma_f32_16x16x32_bf16(
                    w0t[hb][1], bf1, a, 0, 0, 0);
            }
        }

        // ---- stage-finish tile t+1 into A0[buf^1] (lerp/pack/ds_write) ----
        {
            const int sB = (buf ^ 1) * (M_IT * A0S);
            uint4 d;
            d.x = pk2(g1a.x + (g2a.x - g1a.x) * frA, g1a.y + (g2a.y - g1a.y) * frA);
            d.y = pk2(g1a.z + (g2a.z - g1a.z) * frA, g1a.w + (g2a.w - g1a.w) * frA);
            d.z = pk2(g1b.x + (g2b.x - g1b.x) * frA, g1b.y + (g2b.y - g1b.y) * frA);
            d.w = pk2(g1b.z + (g2b.z - g1b.z) * frA, g1b.w + (g2b.w - g1b.w) * frA);
            *(uint4*)&A0[sB + p * A0S + s * 8] = d;
            if (s == 0) *(unsigned*)&A0[sB + p * A0S + 32] = pk2(xvA.x, xvA.y);
        }
        feA = feN; xvA = xvN;   // roll the 2-deep fe/x pipeline

        // epi0: clamp fused into cvt (pk2c); straight to H0.
        #pragma unroll
        for (int pb = 0; pb < 4; ++pb) {
            const f32x4 v0 = acc[pb][0], v1 = acc[pb][1];
            uint4 w;
            w.x = pk2c(v0[0], v0[1]);
            w.y = pk2c(v0[2], v0[3]);
            w.z = pk2c(v1[0], v1[1]);
            w.w = pk2c(v1[2], v1[3]);
            *(uint4*)&H0[(pb * 16 + cl) * H0S + nq * 32 + q * 8] = w;
        }
        bar_lds();   // bar2: H0(t) + stage(t+1) visible; out-reads drained

        // ---- layer 1: all kt from LDS; bias rides C at kk==0 (literal) ----
        #pragma unroll
        for (int kk = 0; kk < 4; ++kk) {
            const int kcol = (((nq + kk) & 3) << 5) + q * 8;  // runtime addr
            #pragma unroll
            for (int pb = 0; pb < 4; ++pb) {
                bf16x8 bfrag = *(const bf16x8*)
                    &H0[(pb * 16 + cl) * H0S + kcol];
                #pragma unroll
                for (int hb = 0; hb < 2; ++hb)
                    acc[pb][hb] = __builtin_amdgcn_mfma_f32_16x16x32_bf16(
                        w1r[hb][kk], bfrag,
                        kk == 0 ? b1q[hb] : acc[pb][hb], 0, 0, 0);
            }
        }

        // ---- layer 2 via MFMA: clamped-h1 frag is the B operand ----------
        const f32x4 zero = {0.f, 0.f, 0.f, 0.f};
        #pragma unroll
        for (int pb = 0; pb < 4; ++pb) {
            const f32x4 v0 = acc[pb][0], v1 = acc[pb][1];
            uint4 w;
            w.x = pk2c(v0[0], v0[1]);
            w.y = pk2c(v0[2], v0[3]);
            w.z = pk2c(v1[0], v1[1]);
            w.w = pk2c(v1[2], v1[3]);
            bf16x8 hf;
            __builtin_memcpy(&hf, &w, 16);
            const f32x4 z4 = __builtin_amdgcn_mfma_f32_16x16x32_bf16(
                w2f, hf, zero, 0, 0, 0);
            if (q == 0)
                *(float*)((char*)A0 + (pb * 16 + cl) * 144 + 128 + nq * 4) = z4[0];
        }
        prev_base = base;
        buf ^= 1;
        // hazards: L0(t) reads A0[buf] vs stage(t+2) writes A0[buf]:
        // bar2(t) + bar1(t+1) between. H0 epi0(t+1) vs L1(t): bar1(t+1).
        // PART(t) (post-bar2) -> out-read(t) (post-bar1(t+1)) -> PART(t+1)
        // (post-bar2(t+1); wave0's out-reads drain at its bar2 entry).
    }

    // epilogue: flush the last tile's deferred out-phase
    bar_lds();
    if (prev_base >= 0 && tid < 64) {
        const float4 pv = *(const float4*)((const char*)A0 + tid * 144 + 128);
        const float zz = bias2 + pv.x + pv.y + pv.z + pv.w;
        out[prev_base + tid] = __builtin_amdgcn_rcpf(1.f + __expf(-zz));
    }
}

extern "C" void kernel_launch(void* const* d_in, const int* in_sizes, int n_in,
                              void* d_out, int out_size, void* d_ws, size_t ws_size,
                              hipStream_t stream) {
    const float* x   = (const float*)d_in[0];
    const float* emb = (const float*)d_in[1];
    const float* emt = (const float*)d_in[2];
    const float* W0  = (const float*)d_in[3];
    const float* b0  = (const float*)d_in[4];
    const float* W1  = (const float*)d_in[5];
    const float* b1  = (const float*)d_in[6];
    const float* W2  = (const float*)d_in[7];
    const float* b2  = (const float*)d_in[8];
    mlp_fused<<<NBLOCKS, 256, 0, stream>>>(x, emb, emt, W0, b0, W1, b1, W2, b2,
                                           (float*)d_out);
}

// Round 16
// 121.450 us; speedup vs baseline: 1.0234x; 1.0234x over previous
//
#include <hip/hip_runtime.h>
#include <hip/hip_bf16.h>

// Fused 34->128->128->1 MLP, bf16 MFMA, transposed GEMMs.
// R26 = R21 (proven best, 57.2us) with the deferred out-phase SPREAD
// across all 4 waves (was: wave 0 alone -> ~200-400cyc L0-entry skew/tile).
// pt = nq*16 + lane (lane<16): each wave reads 16 PART float4s + does 16
// exp/rcp/stores. No structural change: same barriers, same phases, same
// frag patterns, nothing register-live across barriers, no fresh-uninit.
// SESSION VERDICT on restructures: 6/6 NaN (R14/R19/R20/R22/R24/R25)
// across three falsified source-level theories (reg-frag-across-barrier,
// zero-init guard, undef-ternary poison) while R21-shape passed 4/4
// (R15/R18/R21/R23) -> allocation-sensitive codegen hazard; only
// in-shape edits are admissible.
// Kept verbatim from R21: lgkm-only bar_lds (vmcnt stays in flight across
// barriers; __syncthreads' vmcnt(0) drain deleted = +5%), deferred
// out-phase (bar3 deleted = +5%), pk2c clamp-fused cvt, L2-as-MFMA (W2 in
// A-frag row 0), biases ride first MFMA C operand, PART aliased in A0
// cols 64..71 (LDS 26624B, 3 blocks/CU at (256,3)), no own[], w1r
// rotation (literal register indices).
// R8a: phys h = nq*32 + q*8 + hb*4 + r; L0 C/D frag == L1 B frag layout.
// Ledger at R21: MfmaUtil 37 / VALU 28 / LDS ~45% / HBM 3% -> gap-bound;
// remaining gap-levers need restructures the toolchain NaNs.
// Spill tell: WRITE_SIZE == 3906.25KB <=> clean alloc at (256,3).

using bf16x8 = __attribute__((ext_vector_type(8))) short;   // 8 bf16 = 4 VGPRs
using f32x4  = __attribute__((ext_vector_type(4))) float;   // MFMA C/D

#define NPTS    1000000
#define NUMEMB  6572
#define HID     128
#define M_IT    64          // points per block-iteration
#define A0S     72          // A0 row stride in bf16 (144B, 16B-aligned rows)
#define H0S     136         // H0 row stride in bf16 (272B, 16B-aligned rows)
#define TILES   (NPTS / M_IT)   // 15625 exactly
#define NBLOCKS 768         // 3 blocks/CU on 256 CUs (proven non-spill rung)

__device__ __forceinline__ unsigned short bf16r(float f) {
    unsigned u;
    __builtin_memcpy(&u, &f, 4);
    u = (u + 0x7fffu + ((u >> 16) & 1u)) >> 16;
    return (unsigned short)u;
}
__device__ __forceinline__ unsigned pk2(float a, float b) {
    // packed RNE f32x2 -> bf16x2 (v_cvt_pk_bf16_f32 on gfx950)
    float2 f2; f2.x = a; f2.y = b;
    __hip_bfloat162 h = __float22bfloat162_rn(f2);
    unsigned u;
    __builtin_memcpy(&u, &h, 4);
    return u;
}
__device__ __forceinline__ unsigned pk2c(float a, float b) {
    // packed cvt with VOP3 clamp: result clamped to [0,1] — fuses clamp01
    unsigned r;
    asm("v_cvt_pk_bf16_f32 %0, %1, %2 clamp" : "=v"(r) : "v"(a), "v"(b));
    return r;
}
// LDS-only barrier: waits DS/SMEM queue, NOT vmem. Single asm block =>
// nothing schedules between the wait and the barrier; "memory" clobber
// pins all LDS accesses to their side of it. (R18-verified.)
__device__ __forceinline__ void bar_lds() {
    asm volatile("s_waitcnt lgkmcnt(0)\n\ts_barrier" ::: "memory");
}

__global__ __launch_bounds__(256, 3)
void mlp_fused(const float* __restrict__ x,
               const float* __restrict__ emb,
               const float* __restrict__ em_table,
               const float* __restrict__ W0, const float* __restrict__ b0,
               const float* __restrict__ W1, const float* __restrict__ b1,
               const float* __restrict__ W2, const float* __restrict__ b2,
               float* __restrict__ out)
{
    __shared__ __align__(16) unsigned short A0[M_IT * A0S];  // bf16 [pt][in]
    __shared__ __align__(16) unsigned short H0[M_IT * H0S];  // bf16 [pt][hperm]
    // PART[p][w] aliased into A0 bytes p*144 + 128 + w*4 (cols 64..71,
    // never accessed as A0: reads span cols <=63, writes cols <=33).

    const int tid  = threadIdx.x;
    const int lane = tid & 63;
    const int nq   = tid >> 6;   // wave's physical hidden block [nq*32,+32)
    const int q    = lane >> 4;  // quad within wave
    const int cl   = lane & 15;
    const int p    = tid >> 2;   // staging: point within tile
    const int s    = tid & 3;    // staging: 8-dim segment of embedding

    // zero A0 once (cols 34..63 stay zero forever; build overwrites 0..33)
    for (int i = tid; i < M_IT * A0S; i += 256) A0[i] = 0;

    // ---- one-time: weight A-fragments (permuted cols) into registers ----
    const int hcol = nq * 32 + (cl >> 2) * 8 + (cl & 3);  // + hb*4
    // W0 logical row k: k<32 -> em row 2+k ; k==32 -> x row 0 ; k==33 -> 1.
    bf16x8 w0t[2][2];   // [hb][kt]
    for (int hb = 0; hb < 2; ++hb)
        for (int kt = 0; kt < 2; ++kt) {
            const int col = hcol + hb * 4;
            bf16x8 v;
            #pragma unroll
            for (int e = 0; e < 8; ++e) {
                const int k = kt * 32 + q * 8 + e;
                float val = 0.f;
                if (k < 32)       val = W0[(2 + k) * HID + col];
                else if (k == 32) val = W0[0 * HID + col];
                else if (k == 33) val = W0[1 * HID + col];
                v[e] = (short)bf16r(val);
            }
            w0t[hb][kt] = v;
        }

    // W1 ROTATED: w1r[hb][kk] holds rows kphys = ((nq+kk)&3)*32 + q*8 + e
    bf16x8 w1r[2][4];   // [hb][kk]
    for (int hb = 0; hb < 2; ++hb)
        for (int kk = 0; kk < 4; ++kk) {
            const int kt  = (nq + kk) & 3;
            const int col = hcol + hb * 4;
            bf16x8 v;
            #pragma unroll
            for (int e = 0; e < 8; ++e) {
                const int k = kt * 32 + q * 8 + e;
                v[e] = (short)bf16r(W1[k * HID + col]);
            }
            w1r[hb][kk] = v;
        }

    // biases indexed by this lane's physical h = nq*32 + q*8 + hb*4 + r
    f32x4 b0q[2], b1q[2];
    for (int hb = 0; hb < 2; ++hb)
        for (int r = 0; r < 4; ++r) {
            const int h = nq * 32 + q * 8 + hb * 4 + r;
            b0q[hb][r] = b0[h];
            b1q[hb][r] = b1[h];
        }
    // L2 A-frag: A[m][k] = (m==0) ? W2[nq*32 + q*8 + k_e] : 0.
    bf16x8 w2f;
    #pragma unroll
    for (int e = 0; e < 8; ++e)
        w2f[e] = (cl == 0) ? (short)bf16r(W2[nq * 32 + q * 8 + e]) : (short)0;
    const float bias2 = b2[0];

    // ---- shallow prefetch: fe/x for the first tile (3 regs) ----
    int t = blockIdx.x;
    float  feA;
    float2 xvA = {0.f, 0.f};
    {
        const int gp = t * M_IT + p;
        feA = emb[gp];
        if (s == 0) xvA = *(const float2*)(x + 2 * gp);
    }

    __syncthreads();   // A0 zeroing visible before first build (cold path)

    int prev_base = -1;   // out-phase is deferred one tile (bar3 deleted)

    for (; t < TILES; t += gridDim.x) {
        const int base = t * M_IT;

        // ---- stage inputs into A0 (gathers start immediately: feA ready) --
        {
            const int e1 = (int)feA;
            const int e2 = (e1 + 1 < NUMEMB) ? e1 + 1 : NUMEMB - 1;
            const float r = feA - (float)e1;
            const float4* p1 = (const float4*)(em_table + e1 * 32 + s * 8);
            const float4* p2 = (const float4*)(em_table + e2 * 32 + s * 8);
            const float4 a0v = p1[0], a1v = p1[1];
            const float4 c0v = p2[0], c1v = p2[1];
            uint4 d;
            d.x = pk2(a0v.x + (c0v.x - a0v.x) * r, a0v.y + (c0v.y - a0v.y) * r);
            d.y = pk2(a0v.z + (c0v.z - a0v.z) * r, a0v.w + (c0v.w - a0v.w) * r);
            d.z = pk2(a1v.x + (c1v.x - a1v.x) * r, a1v.y + (c1v.y - a1v.y) * r);
            d.w = pk2(a1v.z + (c1v.z - a1v.z) * r, a1v.w + (c1v.w - a1v.w) * r);
            *(uint4*)&A0[p * A0S + s * 8] = d;
            if (s == 0) *(unsigned*)&A0[p * A0S + 32] = pk2(xvA.x, xvA.y);
        }
        bar_lds();   // bar1: A0(t) + PART(t-1) visible (LDS-only)

        // ---- deferred out-phase for tile t-1: SPREAD across 4 waves ----
        // pt = nq*16 + lane (lane<16): 16 exp/rcp/stores per wave instead
        // of 64 on wave 0 (removes wave0's L0-entry skew at bar2).
        if (prev_base >= 0 && (lane < 16)) {
            const int pt = nq * 16 + lane;
            const float4 pv = *(const float4*)((const char*)A0 + pt * 144 + 128);
            const float zz = bias2 + pv.x + pv.y + pv.z + pv.w;
            out[prev_base + pt] = __builtin_amdgcn_rcpf(1.f + __expf(-zz));
        }

        // ---- layer 0 (transposed, permuted cols): bias rides C operand ----
        f32x4 acc[4][2];   // [pb][hb]
        #pragma unroll
        for (int pb = 0; pb < 4; ++pb) {
            const bf16x8 bf0 = *(const bf16x8*)&A0[(pb * 16 + cl) * A0S + q * 8];
            const bf16x8 bf1 = *(const bf16x8*)&A0[(pb * 16 + cl) * A0S + 32 + q * 8];
            #pragma unroll
            for (int hb = 0; hb < 2; ++hb) {
                f32x4 a = __builtin_amdgcn_mfma_f32_16x16x32_bf16(
                    w0t[hb][0], bf0, b0q[hb], 0, 0, 0);
                acc[pb][hb] = __builtin_amdgcn_mfma_f32_16x16x32_bf16(
                    w0t[hb][1], bf1, a, 0, 0, 0);
            }
        }

        // prefetch fe/x for next tile — never drained at barriers (lgkm-only)
        {
            int t1 = t + gridDim.x; if (t1 >= TILES) t1 = t;
            const int gp = t1 * M_IT + p;
            feA = emb[gp];
            if (s == 0) xvA = *(const float2*)(x + 2 * gp);
        }

        // epi0: clamp fused into cvt (pk2c); straight to H0 (no own[]).
        #pragma unroll
        for (int pb = 0; pb < 4; ++pb) {
            const f32x4 v0 = acc[pb][0], v1 = acc[pb][1];
            uint4 w;
            w.x = pk2c(v0[0], v0[1]);
            w.y = pk2c(v0[2], v0[3]);
            w.z = pk2c(v1[0], v1[1]);
            w.w = pk2c(v1[2], v1[3]);
            *(uint4*)&H0[(pb * 16 + cl) * H0S + nq * 32 + q * 8] = w;
        }
        bar_lds();   // bar2: H0 visible; each wave's out-reads drained at its
                     // own entry (lgkmcnt(0)); PART(t) writes come after

        // ---- layer 1: all kt from LDS; bias rides C at kk==0 (literal) ----
        #pragma unroll
        for (int kk = 0; kk < 4; ++kk) {
            const int kcol = (((nq + kk) & 3) << 5) + q * 8;  // runtime addr
            #pragma unroll
            for (int pb = 0; pb < 4; ++pb) {
                bf16x8 bfrag = *(const bf16x8*)
                    &H0[(pb * 16 + cl) * H0S + kcol];
                #pragma unroll
                for (int hb = 0; hb < 2; ++hb)
                    acc[pb][hb] = __builtin_amdgcn_mfma_f32_16x16x32_bf16(
                        w1r[hb][kk], bfrag,
                        kk == 0 ? b1q[hb] : acc[pb][hb], 0, 0, 0);
            }
        }

        // ---- layer 2 via MFMA: clamped-h1 frag is the B operand ----------
        const f32x4 zero = {0.f, 0.f, 0.f, 0.f};
        #pragma unroll
        for (int pb = 0; pb < 4; ++pb) {
            const f32x4 v0 = acc[pb][0], v1 = acc[pb][1];
            uint4 w;
            w.x = pk2c(v0[0], v0[1]);
            w.y = pk2c(v0[2], v0[3]);
            w.z = pk2c(v1[0], v1[1]);
            w.w = pk2c(v1[2], v1[3]);
            bf16x8 hf;
            __builtin_memcpy(&hf, &w, 16);
            const f32x4 z4 = __builtin_amdgcn_mfma_f32_16x16x32_bf16(
                w2f, hf, zero, 0, 0, 0);
            if (q == 0)
                *(float*)((char*)A0 + (pb * 16 + cl) * 144 + 128 + nq * 4) = z4[0];
        }
        prev_base = base;   // out for this tile happens after next bar1

        // hazards: A0 cols0..33 rewrite (next stage) vs L0(t) reads -> bar2;
        // H0 rewrite (epi0 t+1) vs L1(t) reads -> bar1(t+1); PART(t) write
        // (post-bar2) -> out-read(t) (post-bar1(t+1), all waves) ->
        // PART(t+1) write (post-bar2(t+1); every wave's out-read drains at
        // its own bar2 entry). Stage writes cols 0..33, out reads bytes
        // 128..143: disjoint.
    }

    // epilogue: flush the last tile's deferred out-phase
    bar_lds();
    if (prev_base >= 0 && (lane < 16)) {
        const int pt = nq * 16 + lane;
        const float4 pv = *(const float4*)((const char*)A0 + pt * 144 + 128);
        const float zz = bias2 + pv.x + pv.y + pv.z + pv.w;
        out[prev_base + pt] = __builtin_amdgcn_rcpf(1.f + __expf(-zz));
    }
}

extern "C" void kernel_launch(void* const* d_in, const int* in_sizes, int n_in,
                              void* d_out, int out_size, void* d_ws, size_t ws_size,
                              hipStream_t stream) {
    const float* x   = (const float*)d_in[0];
    const float* emb = (const float*)d_in[1];
    const float* emt = (const float*)d_in[2];
    const float* W0  = (const float*)d_in[3];
    const float* b0  = (const float*)d_in[4];
    const float* W1  = (const float*)d_in[5];
    const float* b1  = (const float*)d_in[6];
    const float* W2  = (const float*)d_in[7];
    const float* b2  = (const float*)d_in[8];
    mlp_fused<<<NBLOCKS, 256, 0, stream>>>(x, emb, emt, W0, b0, W1, b1, W2, b2,
                                           (float*)d_out);
}

// Round 17
// 121.017 us; speedup vs baseline: 1.0271x; 1.0036x over previous
//
#include <hip/hip_runtime.h>
#include <hip/hip_bf16.h>

// Fused 34->128->128->1 MLP, bf16 MFMA, transposed GEMMs.
// R27 = R21 VERBATIM (session optimum: 57.2us/dispatch, 120.6us bench) —
// locked in as final after the full neighborhood was measured:
//   in-shape neighbors: R23 dbuf+hoist +3.2us, R26 out-spread +3.9us,
//     R15/R18 ancestors +3.1us -> R21 is the local optimum.
//   structural neighbors: 6/6 NaN (R14/R19/R20/R22/R24/R25) across three
//     falsified source-level theories (reg-frag-across-barrier, zero-init
//     guard, undef-ternary poison) -> allocation-sensitive codegen hazard;
//     restructures inadmissible on this toolchain.
// Counters at optimum: MfmaUtil 37 / VALUBusy 28 / LDS ~45% / HBM 3% —
// NOT a hardware roofline; a toolchain-constrained floor (the MfmaUtil
// levers all live in the NaN cell).
// Verified wins accumulated here (vs 126.5us session baseline):
//  - lgkm-only barriers: __syncthreads' vmcnt(0) drain deleted; prefetch
//    loads stay in flight across barriers (R18, +5%).
//  - bar3 deleted via out-phase deferral: out(t-1) overlaps L0(t) after
//    bar1; 2 barriers/tile (R21, +5%).
//  - VALU diet (R11, verified R15): clamp01 fused into v_cvt_pk_bf16_f32
//    clamp (pk2c); L2 as MFMA (W2 in A-frag row 0, kills 64-op dot +
//    16-row reduce); biases ride first MFMA's C operand. VALUBusy 45->26.
//  - PART aliased into A0 cols 64..71: LDS 26624B, 3 blocks/CU at (256,3),
//    the only non-spilling rung (R12/R13/R17: all higher rungs spill ~14.5MB
//    or queue serially; WRITE_SIZE==3906.25KB is the spill tell).
// R8a: phys h = nq*32 + q*8 + hb*4 + r; L0 C/D frag == L1 B frag layout;
// w1r rotation keeps L1 register indices literal.

using bf16x8 = __attribute__((ext_vector_type(8))) short;   // 8 bf16 = 4 VGPRs
using f32x4  = __attribute__((ext_vector_type(4))) float;   // MFMA C/D

#define NPTS    1000000
#define NUMEMB  6572
#define HID     128
#define M_IT    64          // points per block-iteration
#define A0S     72          // A0 row stride in bf16 (144B, 16B-aligned rows)
#define H0S     136         // H0 row stride in bf16 (272B, 16B-aligned rows)
#define TILES   (NPTS / M_IT)   // 15625 exactly
#define NBLOCKS 768         // 3 blocks/CU on 256 CUs (proven non-spill rung)

__device__ __forceinline__ unsigned short bf16r(float f) {
    unsigned u;
    __builtin_memcpy(&u, &f, 4);
    u = (u + 0x7fffu + ((u >> 16) & 1u)) >> 16;
    return (unsigned short)u;
}
__device__ __forceinline__ unsigned pk2(float a, float b) {
    // packed RNE f32x2 -> bf16x2 (v_cvt_pk_bf16_f32 on gfx950)
    float2 f2; f2.x = a; f2.y = b;
    __hip_bfloat162 h = __float22bfloat162_rn(f2);
    unsigned u;
    __builtin_memcpy(&u, &h, 4);
    return u;
}
__device__ __forceinline__ unsigned pk2c(float a, float b) {
    // packed cvt with VOP3 clamp: result clamped to [0,1] — fuses clamp01
    unsigned r;
    asm("v_cvt_pk_bf16_f32 %0, %1, %2 clamp" : "=v"(r) : "v"(a), "v"(b));
    return r;
}
// LDS-only barrier: waits DS/SMEM queue, NOT vmem. Single asm block =>
// nothing schedules between the wait and the barrier; "memory" clobber
// pins all LDS accesses to their side of it. (R18-verified.)
__device__ __forceinline__ void bar_lds() {
    asm volatile("s_waitcnt lgkmcnt(0)\n\ts_barrier" ::: "memory");
}

__global__ __launch_bounds__(256, 3)
void mlp_fused(const float* __restrict__ x,
               const float* __restrict__ emb,
               const float* __restrict__ em_table,
               const float* __restrict__ W0, const float* __restrict__ b0,
               const float* __restrict__ W1, const float* __restrict__ b1,
               const float* __restrict__ W2, const float* __restrict__ b2,
               float* __restrict__ out)
{
    __shared__ __align__(16) unsigned short A0[M_IT * A0S];  // bf16 [pt][in]
    __shared__ __align__(16) unsigned short H0[M_IT * H0S];  // bf16 [pt][hperm]
    // PART[p][w] aliased into A0 bytes p*144 + 128 + w*4 (cols 64..71,
    // never accessed as A0: reads span cols <=63, writes cols <=33).

    const int tid  = threadIdx.x;
    const int lane = tid & 63;
    const int nq   = tid >> 6;   // wave's physical hidden block [nq*32,+32)
    const int q    = lane >> 4;  // quad within wave
    const int cl   = lane & 15;
    const int p    = tid >> 2;   // staging: point within tile
    const int s    = tid & 3;    // staging: 8-dim segment of embedding

    // zero A0 once (cols 34..63 stay zero forever; build overwrites 0..33)
    for (int i = tid; i < M_IT * A0S; i += 256) A0[i] = 0;

    // ---- one-time: weight A-fragments (permuted cols) into registers ----
    const int hcol = nq * 32 + (cl >> 2) * 8 + (cl & 3);  // + hb*4
    // W0 logical row k: k<32 -> em row 2+k ; k==32 -> x row 0 ; k==33 -> 1.
    bf16x8 w0t[2][2];   // [hb][kt]
    for (int hb = 0; hb < 2; ++hb)
        for (int kt = 0; kt < 2; ++kt) {
            const int col = hcol + hb * 4;
            bf16x8 v;
            #pragma unroll
            for (int e = 0; e < 8; ++e) {
                const int k = kt * 32 + q * 8 + e;
                float val = 0.f;
                if (k < 32)       val = W0[(2 + k) * HID + col];
                else if (k == 32) val = W0[0 * HID + col];
                else if (k == 33) val = W0[1 * HID + col];
                v[e] = (short)bf16r(val);
            }
            w0t[hb][kt] = v;
        }

    // W1 ROTATED: w1r[hb][kk] holds rows kphys = ((nq+kk)&3)*32 + q*8 + e
    bf16x8 w1r[2][4];   // [hb][kk]
    for (int hb = 0; hb < 2; ++hb)
        for (int kk = 0; kk < 4; ++kk) {
            const int kt  = (nq + kk) & 3;
            const int col = hcol + hb * 4;
            bf16x8 v;
            #pragma unroll
            for (int e = 0; e < 8; ++e) {
                const int k = kt * 32 + q * 8 + e;
                v[e] = (short)bf16r(W1[k * HID + col]);
            }
            w1r[hb][kk] = v;
        }

    // biases indexed by this lane's physical h = nq*32 + q*8 + hb*4 + r
    f32x4 b0q[2], b1q[2];
    for (int hb = 0; hb < 2; ++hb)
        for (int r = 0; r < 4; ++r) {
            const int h = nq * 32 + q * 8 + hb * 4 + r;
            b0q[hb][r] = b0[h];
            b1q[hb][r] = b1[h];
        }
    // L2 A-frag: A[m][k] = (m==0) ? W2[nq*32 + q*8 + k_e] : 0.
    bf16x8 w2f;
    #pragma unroll
    for (int e = 0; e < 8; ++e)
        w2f[e] = (cl == 0) ? (short)bf16r(W2[nq * 32 + q * 8 + e]) : (short)0;
    const float bias2 = b2[0];

    // ---- shallow prefetch: fe/x for the first tile (3 regs) ----
    int t = blockIdx.x;
    float  feA;
    float2 xvA = {0.f, 0.f};
    {
        const int gp = t * M_IT + p;
        feA = emb[gp];
        if (s == 0) xvA = *(const float2*)(x + 2 * gp);
    }

    __syncthreads();   // A0 zeroing visible before first build (cold path)

    int prev_base = -1;   // out-phase is deferred one tile (bar3 deleted)

    for (; t < TILES; t += gridDim.x) {
        const int base = t * M_IT;

        // ---- stage inputs into A0 (gathers start immediately: feA ready) --
        {
            const int e1 = (int)feA;
            const int e2 = (e1 + 1 < NUMEMB) ? e1 + 1 : NUMEMB - 1;
            const float r = feA - (float)e1;
            const float4* p1 = (const float4*)(em_table + e1 * 32 + s * 8);
            const float4* p2 = (const float4*)(em_table + e2 * 32 + s * 8);
            const float4 a0v = p1[0], a1v = p1[1];
            const float4 c0v = p2[0], c1v = p2[1];
            uint4 d;
            d.x = pk2(a0v.x + (c0v.x - a0v.x) * r, a0v.y + (c0v.y - a0v.y) * r);
            d.y = pk2(a0v.z + (c0v.z - a0v.z) * r, a0v.w + (c0v.w - a0v.w) * r);
            d.z = pk2(a1v.x + (c1v.x - a1v.x) * r, a1v.y + (c1v.y - a1v.y) * r);
            d.w = pk2(a1v.z + (c1v.z - a1v.z) * r, a1v.w + (c1v.w - a1v.w) * r);
            *(uint4*)&A0[p * A0S + s * 8] = d;
            if (s == 0) *(unsigned*)&A0[p * A0S + 32] = pk2(xvA.x, xvA.y);
        }
        bar_lds();   // bar1: A0(t) + PART(t-1) visible (LDS-only)

        // ---- deferred out-phase for tile t-1 (wave 0; overlaps L0 below,
        //      R26 measured: spreading across waves regresses) ----
        if (prev_base >= 0 && tid < 64) {
            const float4 pv = *(const float4*)((const char*)A0 + tid * 144 + 128);
            const float zz = bias2 + pv.x + pv.y + pv.z + pv.w;
            out[prev_base + tid] = __builtin_amdgcn_rcpf(1.f + __expf(-zz));
        }

        // ---- layer 0 (transposed, permuted cols): bias rides C operand ----
        f32x4 acc[4][2];   // [pb][hb]
        #pragma unroll
        for (int pb = 0; pb < 4; ++pb) {
            const bf16x8 bf0 = *(const bf16x8*)&A0[(pb * 16 + cl) * A0S + q * 8];
            const bf16x8 bf1 = *(const bf16x8*)&A0[(pb * 16 + cl) * A0S + 32 + q * 8];
            #pragma unroll
            for (int hb = 0; hb < 2; ++hb) {
                f32x4 a = __builtin_amdgcn_mfma_f32_16x16x32_bf16(
                    w0t[hb][0], bf0, b0q[hb], 0, 0, 0);
                acc[pb][hb] = __builtin_amdgcn_mfma_f32_16x16x32_bf16(
                    w0t[hb][1], bf1, a, 0, 0, 0);
            }
        }

        // prefetch fe/x for next tile — never drained at barriers (lgkm-only)
        {
            int t1 = t + gridDim.x; if (t1 >= TILES) t1 = t;
            const int gp = t1 * M_IT + p;
            feA = emb[gp];
            if (s == 0) xvA = *(const float2*)(x + 2 * gp);
        }

        // epi0: clamp fused into cvt (pk2c); straight to H0 (no own[]).
        #pragma unroll
        for (int pb = 0; pb < 4; ++pb) {
            const f32x4 v0 = acc[pb][0], v1 = acc[pb][1];
            uint4 w;
            w.x = pk2c(v0[0], v0[1]);
            w.y = pk2c(v0[2], v0[3]);
            w.z = pk2c(v1[0], v1[1]);
            w.w = pk2c(v1[2], v1[3]);
            *(uint4*)&H0[(pb * 16 + cl) * H0S + nq * 32 + q * 8] = w;
        }
        bar_lds();   // bar2: H0 visible; wave0's out-reads drained at its own
                     // lgkmcnt before entering (PART(t) writes come after)

        // ---- layer 1: all kt from LDS; bias rides C at kk==0 (literal) ----
        #pragma unroll
        for (int kk = 0; kk < 4; ++kk) {
            const int kcol = (((nq + kk) & 3) << 5) + q * 8;  // runtime addr
            #pragma unroll
            for (int pb = 0; pb < 4; ++pb) {
                bf16x8 bfrag = *(const bf16x8*)
                    &H0[(pb * 16 + cl) * H0S + kcol];
                #pragma unroll
                for (int hb = 0; hb < 2; ++hb)
                    acc[pb][hb] = __builtin_amdgcn_mfma_f32_16x16x32_bf16(
                        w1r[hb][kk], bfrag,
                        kk == 0 ? b1q[hb] : acc[pb][hb], 0, 0, 0);
            }
        }

        // ---- layer 2 via MFMA: clamped-h1 frag is the B operand ----------
        const f32x4 zero = {0.f, 0.f, 0.f, 0.f};
        #pragma unroll
        for (int pb = 0; pb < 4; ++pb) {
            const f32x4 v0 = acc[pb][0], v1 = acc[pb][1];
            uint4 w;
            w.x = pk2c(v0[0], v0[1]);
            w.y = pk2c(v0[2], v0[3]);
            w.z = pk2c(v1[0], v1[1]);
            w.w = pk2c(v1[2], v1[3]);
            bf16x8 hf;
            __builtin_memcpy(&hf, &w, 16);
            const f32x4 z4 = __builtin_amdgcn_mfma_f32_16x16x32_bf16(
                w2f, hf, zero, 0, 0, 0);
            if (q == 0)
                *(float*)((char*)A0 + (pb * 16 + cl) * 144 + 128 + nq * 4) = z4[0];
        }
        prev_base = base;   // out for this tile happens after next bar1

        // hazards: A0 cols0..33 rewrite (next stage) vs L0(t) reads -> bar2;
        // H0 rewrite (epi0 t+1) vs L1(t) reads -> bar1(t+1); PART(t) write
        // (post-bar2) -> out-read(t) (post-bar1(t+1)) -> PART(t+1) write
        // (post-bar2(t+1); wave0's out-reads drain at its bar2 entry).
        // Stage writes cols 0..33, out reads bytes 128..143: disjoint.
    }

    // epilogue: flush the last tile's deferred out-phase
    bar_lds();
    if (prev_base >= 0 && tid < 64) {
        const float4 pv = *(const float4*)((const char*)A0 + tid * 144 + 128);
        const float zz = bias2 + pv.x + pv.y + pv.z + pv.w;
        out[prev_base + tid] = __builtin_amdgcn_rcpf(1.f + __expf(-zz));
    }
}

extern "C" void kernel_launch(void* const* d_in, const int* in_sizes, int n_in,
                              void* d_out, int out_size, void* d_ws, size_t ws_size,
                              hipStream_t stream) {
    const float* x   = (const float*)d_in[0];
    const float* emb = (const float*)d_in[1];
    const float* emt = (const float*)d_in[2];
    const float* W0  = (const float*)d_in[3];
    const float* b0  = (const float*)d_in[4];
    const float* W1  = (const float*)d_in[5];
    const float* b1  = (const float*)d_in[6];
    const float* W2  = (const float*)d_in[7];
    const float* b2  = (const float*)d_in[8];
    mlp_fused<<<NBLOCKS, 256, 0, stream>>>(x, emb, emt, W0, b0, W1, b1, W2, b2,
                                           (float*)d_out);
}